// Round 1
// baseline (54363.422 us; speedup 1.0000x reference)
//
#include <hip/hip_runtime.h>
#include <math.h>

constexpr int kB  = 128;
constexpr int kT  = 1024;
constexpr int kD  = 32;
constexpr int kH  = 64;
constexpr int kW  = 128;
constexpr int kC  = kD + 1;    // 33
constexpr int kO  = kH * kC;   // 2112
constexpr int kIN = kH + 1;    // 65
constexpr int BLOCK = 256;

__device__ __forceinline__ float fast_sigmoid(float x) { return 1.0f / (1.0f + __expf(-x)); }
__device__ __forceinline__ float lipswish_f(float x)   { return 0.909f * x * fast_sigmoid(x); }
__device__ __forceinline__ float fast_tanh(float x) {
    float ax = fabsf(x);
    float e  = __expf(2.0f * ax);
    float r  = 1.0f - 2.0f / (e + 1.0f);
    return copysignf(r, x);
}

// vf MLP: s_inp[65] -> z1[128] -> z2[128] -> v[2112] (tanh). Streams vW* from global.
__device__ __forceinline__ void vf_layers(
    int t,
    const float* __restrict__ vW0, const float* __restrict__ vb0,
    const float* __restrict__ vW1, const float* __restrict__ vb1,
    const float* __restrict__ vW2, const float* __restrict__ vb2,
    const float* s_inp, float* s_z1, float* s_z2, float* s_v)
{
    // layer 1: 65 -> 128
    if (t < kW) {
        const float* wrow = vW0 + t * kIN;
        float acc = vb0[t];
        #pragma unroll
        for (int c = 0; c < kIN; c++) acc += wrow[c] * s_inp[c];
        s_z1[t] = lipswish_f(acc);
    }
    __syncthreads();
    // layer 2: 128 -> 128
    if (t < kW) {
        const float4* wr  = (const float4*)(vW1 + t * kW);
        const float4* z14 = (const float4*)s_z1;
        float acc = vb1[t];
        #pragma unroll 8
        for (int q = 0; q < kW / 4; q++) {
            float4 w = wr[q]; float4 z = z14[q];
            acc += w.x * z.x + w.y * z.y + w.z * z.z + w.w * z.w;
        }
        s_z2[t] = lipswish_f(acc);
    }
    __syncthreads();
    // layer 3: 128 -> 2112, tanh.  rows n = t + 256*j, j=0..8 (j=8 only wave 0)
    float acc[9];
    #pragma unroll
    for (int j = 0; j < 9; j++) {
        int n = t + BLOCK * j;
        acc[j] = (n < kO) ? vb2[n] : 0.0f;
    }
    const float4* z4 = (const float4*)s_z2;
    #pragma unroll 4
    for (int q = 0; q < kW / 4; q++) {
        float4 z = z4[q];
        #pragma unroll
        for (int j = 0; j < 9; j++) {
            int n = t + BLOCK * j;
            if (n < kO) {
                float4 w = *(const float4*)(vW2 + (size_t)n * kW + 4 * q);
                acc[j] += w.x * z.x + w.y * z.y + w.z * z.z + w.w * z.w;
            }
        }
    }
    #pragma unroll
    for (int j = 0; j < 9; j++) {
        int n = t + BLOCK * j;
        if (n < kO) s_v[n] = fast_tanh(acc[j]);
    }
}

__global__ __launch_bounds__(BLOCK)
void cde_kernel(
    const float* __restrict__ ts,  const float* __restrict__ ys,
    const float* __restrict__ iW0, const float* __restrict__ ib0,
    const float* __restrict__ iW1, const float* __restrict__ ib1,
    const float* __restrict__ iW2, const float* __restrict__ ib2,
    const float* __restrict__ vW0, const float* __restrict__ vb0,
    const float* __restrict__ vW1, const float* __restrict__ vb1,
    const float* __restrict__ vW2, const float* __restrict__ vb2,
    const float* __restrict__ rW,  const float* __restrict__ rb,
    float* __restrict__ out)
{
    const int b = blockIdx.x;
    const int t = threadIdx.x;

    __shared__ float s_v[kO];                 // 2112
    __shared__ float s_y[kH], s_yhat[kH], s_e[kH];
    __shared__ float s_inp[kIN];              // 65
    __shared__ float s_z1[kW], s_z2[kW];
    __shared__ float s_dx[kC], s_xprev[kC];

    const float* ysb = ys + (size_t)b * kT * kD;

    // ---- x0
    if (t < kC) s_xprev[t] = (t == 0) ? ts[0] : ysb[t - 1];
    __syncthreads();

    // ---- initial_mlp: relu(iW0 x0), relu(iW1 z), iW2 z -> y0
    if (t < kW) {
        const float* wrow = iW0 + t * kC;
        float acc = ib0[t];
        #pragma unroll
        for (int c = 0; c < kC; c++) acc += wrow[c] * s_xprev[c];
        s_z1[t] = fmaxf(acc, 0.0f);
    }
    __syncthreads();
    if (t < kW) {
        const float4* wr  = (const float4*)(iW1 + t * kW);
        const float4* z14 = (const float4*)s_z1;
        float acc = ib1[t];
        #pragma unroll 8
        for (int q = 0; q < kW / 4; q++) {
            float4 w = wr[q]; float4 z = z14[q];
            acc += w.x * z.x + w.y * z.y + w.z * z.z + w.w * z.w;
        }
        s_z2[t] = fmaxf(acc, 0.0f);
    }
    __syncthreads();
    if (t < kH) {
        const float4* wr  = (const float4*)(iW2 + t * kW);
        const float4* z24 = (const float4*)s_z2;
        float acc = ib2[t];
        #pragma unroll 8
        for (int q = 0; q < kW / 4; q++) {
            float4 w = wr[q]; float4 z = z24[q];
            acc += w.x * z.x + w.y * z.y + w.z * z.z + w.w * z.w;
        }
        s_y[t] = acc; s_yhat[t] = acc;
        s_inp[1 + t] = acc;
    }
    if (t == 0) s_inp[0] = ts[0];
    __syncthreads();

    // ---- vf0
    vf_layers(t, vW0, vb0, vW1, vb1, vW2, vb2, s_inp, s_z1, s_z2, s_v);
    __syncthreads();

    // ---- scan: i = 1 .. T-1
    for (int i = 1; i < kT; i++) {
        float t1 = ts[i];
        if (t < kC) {
            float xc = (t == 0) ? t1 : ysb[i * kD + (t - 1)];
            s_dx[t] = xc - s_xprev[t];
            s_xprev[t] = xc;
        }
        __syncthreads();
        // e = einsum(v, dx); yhat1 = 2y - yhat + e
        if (t < kH) {
            const float* vr = s_v + t * kC;
            float acc = 0.0f;
            #pragma unroll
            for (int c = 0; c < kC; c++) acc += vr[c] * s_dx[c];
            s_e[t] = acc;
            float yh1 = 2.0f * s_y[t] - s_yhat[t] + acc;
            s_yhat[t] = yh1;
            s_inp[1 + t] = yh1;
        }
        if (t == 0) s_inp[0] = t1;
        __syncthreads();
        // v1 = vf(t1, yhat1)   (overwrites s_v; e already captured)
        vf_layers(t, vW0, vb0, vW1, vb1, vW2, vb2, s_inp, s_z1, s_z2, s_v);
        __syncthreads();
        // y1 = y + 0.5*(e + einsum(v1, dx))
        if (t < kH) {
            const float* vr = s_v + t * kC;
            float acc = 0.0f;
            #pragma unroll
            for (int c = 0; c < kC; c++) acc += vr[c] * s_dx[c];
            s_y[t] += 0.5f * (s_e[t] + acc);
        }
        __syncthreads();
    }

    // ---- readout: out[b] = y . rW + rb
    if (t == 0) {
        float acc = rb[0];
        #pragma unroll
        for (int h = 0; h < kH; h++) acc += s_y[h] * rW[h];
        out[b] = acc;
    }
}

extern "C" void kernel_launch(void* const* d_in, const int* in_sizes, int n_in,
                              void* d_out, int out_size, void* d_ws, size_t ws_size,
                              hipStream_t stream)
{
    const float* ts  = (const float*)d_in[0];
    const float* ys  = (const float*)d_in[1];
    const float* iW0 = (const float*)d_in[2];
    const float* ib0 = (const float*)d_in[3];
    const float* iW1 = (const float*)d_in[4];
    const float* ib1 = (const float*)d_in[5];
    const float* iW2 = (const float*)d_in[6];
    const float* ib2 = (const float*)d_in[7];
    const float* vW0 = (const float*)d_in[8];
    const float* vb0 = (const float*)d_in[9];
    const float* vW1 = (const float*)d_in[10];
    const float* vb1 = (const float*)d_in[11];
    const float* vW2 = (const float*)d_in[12];
    const float* vb2 = (const float*)d_in[13];
    const float* rW  = (const float*)d_in[14];
    const float* rb  = (const float*)d_in[15];
    float* out = (float*)d_out;

    hipLaunchKernelGGL(cde_kernel, dim3(kB), dim3(BLOCK), 0, stream,
                       ts, ys, iW0, ib0, iW1, ib1, iW2, ib2,
                       vW0, vb0, vW1, vb1, vW2, vb2, rW, rb, out);
}

// Round 2
// 29849.579 us; speedup vs baseline: 1.8212x; 1.8212x over previous
//
#include <hip/hip_runtime.h>
#include <math.h>

constexpr int kB  = 128;
constexpr int kT  = 1024;
constexpr int kD  = 32;
constexpr int kH  = 64;
constexpr int kW  = 128;
constexpr int kC  = kD + 1;    // 33
constexpr int kO  = kH * kC;   // 2112
constexpr int kIN = kH + 1;    // 65
constexpr int BLOCK = 1024;    // 16 waves

__device__ __forceinline__ float fast_sigmoid(float x) { return 1.0f / (1.0f + __expf(-x)); }
__device__ __forceinline__ float lipswish_f(float x)   { return 0.909f * x * fast_sigmoid(x); }
__device__ __forceinline__ float fast_tanh(float x) {
    float ax = fabsf(x);
    float e  = __expf(2.0f * ax);
    float r  = 1.0f - 2.0f / (e + 1.0f);
    return copysignf(r, x);
}
__device__ __forceinline__ float dot4(float4 a, float4 b) {
    return a.x * b.x + a.y * b.y + a.z * b.z + a.w * b.w;
}

__global__ __launch_bounds__(BLOCK, 1)
void cde_kernel(
    const float* __restrict__ ts,  const float* __restrict__ ys,
    const float* __restrict__ iW0, const float* __restrict__ ib0,
    const float* __restrict__ iW1, const float* __restrict__ ib1,
    const float* __restrict__ iW2, const float* __restrict__ ib2,
    const float* __restrict__ vW0, const float* __restrict__ vb0,
    const float* __restrict__ vW1, const float* __restrict__ vb1,
    const float* __restrict__ vW2, const float* __restrict__ vb2,
    const float* __restrict__ rW,  const float* __restrict__ rb,
    float* __restrict__ out)
{
    const int b  = blockIdx.x;
    const int t  = threadIdx.x;
    const int r8 = t >> 3;     // 0..127 : row index for split-k phases
    const int g  = t & 7;      // 0..7   : k-group

    __shared__ float s_v[kO];           // v, flat n = h*33+c
    __shared__ float s_z1[kW], s_z2[kW];
    __shared__ float s_inp[kIN];
    __shared__ float s_y[kH], s_yhat[kH], s_e[kH];
    __shared__ float s_dx[kC];

    const float* ysb = ys + (size_t)b * kT * kD;

    // ---------------- register-resident vW2 rows t and t+1024 ----------------
    float4 wA[32], wB[32];
    {
        const float4* rowA = (const float4*)(vW2 + (size_t)t * kW);
        const float4* rowB = (const float4*)(vW2 + (size_t)(t + 1024) * kW);
        #pragma unroll
        for (int q = 0; q < 32; q++) { wA[q] = rowA[q]; wB[q] = rowB[q]; }
    }
    const float bA = vb2[t];
    const float bB = vb2[t + 1024];
    const float bTl = (t < 512) ? vb2[2048 + r8] : 0.0f;   // tail row bias
    const float b0r = vb0[r8];
    const float b1r = vb1[r8];

    // ---------------- x0 + prefetch x1 (held in regs by t<33) ----------------
    float x_reg = 0.0f, x_next = 0.0f;
    if (t < kC) {
        x_reg  = (t == 0) ? ts[0] : ysb[t - 1];
        x_next = (t == 0) ? ts[1] : ysb[kD + (t - 1)];
        s_dx[t] = x_reg;                 // temp: stage x0 for initial MLP
    }
    __syncthreads();

    // ---------------- initial MLP (one-time, one-thread-per-row) -------------
    if (t < kW) {
        const float* wrow = iW0 + t * kC;
        float acc = ib0[t];
        #pragma unroll
        for (int c = 0; c < kC; c++) acc += wrow[c] * s_dx[c];
        s_z1[t] = fmaxf(acc, 0.0f);
    }
    __syncthreads();
    if (t < kW) {
        const float4* wr = (const float4*)(iW1 + t * kW);
        const float4* z4 = (const float4*)s_z1;
        float acc = ib1[t];
        #pragma unroll 8
        for (int q = 0; q < kW / 4; q++) acc += dot4(wr[q], z4[q]);
        s_z2[t] = fmaxf(acc, 0.0f);
    }
    __syncthreads();
    if (t < kH) {
        const float4* wr = (const float4*)(iW2 + t * kW);
        const float4* z4 = (const float4*)s_z2;
        float acc = ib2[t];
        #pragma unroll 8
        for (int q = 0; q < kW / 4; q++) acc += dot4(wr[q], z4[q]);
        s_y[t] = acc; s_yhat[t] = acc;
        s_inp[1 + t] = acc;
    }
    if (t == 0) s_inp[0] = x_reg;        // ts[0]
    __syncthreads();

    // ---------------- main scan ----------------
    for (int i = 0; i < kT; i++) {
        // ===== vf(s_inp) -> s_v =====
        // layer 1: 65 -> 128, split-k: row r8, cols c = g + 8m
        {
            float acc = 0.0f;
            #pragma unroll
            for (int m = 0; m < 9; m++) {
                int c = g + 8 * m;
                if (c < kIN) acc += vW0[r8 * kIN + c] * s_inp[c];
            }
            acc += __shfl_xor(acc, 1);
            acc += __shfl_xor(acc, 2);
            acc += __shfl_xor(acc, 4);
            if (g == 0) s_z1[r8] = lipswish_f(b0r + acc);
        }
        __syncthreads();
        // layer 2: 128 -> 128, split-k float4: cols 4g + 32m
        {
            float acc = 0.0f;
            #pragma unroll
            for (int m = 0; m < 4; m++) {
                int c0 = 4 * g + 32 * m;
                float4 w = *(const float4*)(vW1 + r8 * kW + c0);
                float4 z = *(const float4*)(s_z1 + c0);
                acc += dot4(w, z);
            }
            acc += __shfl_xor(acc, 1);
            acc += __shfl_xor(acc, 2);
            acc += __shfl_xor(acc, 4);
            if (g == 0) s_z2[r8] = lipswish_f(b1r + acc);
        }
        __syncthreads();
        // layer 3 main: rows t, t+1024 from registers; z2 broadcast from LDS
        {
            float acc0 = bA, acc1 = bB;
            const float4* z4 = (const float4*)s_z2;
            #pragma unroll
            for (int q = 0; q < 32; q++) {
                float4 z = z4[q];
                acc0 += dot4(wA[q], z);
                acc1 += dot4(wB[q], z);
            }
            s_v[t]        = fast_tanh(acc0);
            s_v[t + 1024] = fast_tanh(acc1);
        }
        // layer 3 tail: rows 2048..2111, split-k over waves 0..7
        if (t < 512) {
            int rt = 2048 + r8;          // r8 in 0..63
            float acc = 0.0f;
            #pragma unroll
            for (int m = 0; m < 4; m++) {
                int c0 = 4 * g + 32 * m;
                float4 w = *(const float4*)(vW2 + (size_t)rt * kW + c0);
                float4 z = *(const float4*)(s_z2 + c0);
                acc += dot4(w, z);
            }
            acc += __shfl_xor(acc, 1);
            acc += __shfl_xor(acc, 2);
            acc += __shfl_xor(acc, 4);
            if (g == 0) s_v[rt] = fast_tanh(bTl + acc);
        }
        __syncthreads();

        // ===== y update: y += 0.5*(e + v_new . dx)  (uses dx_i, e_i) =====
        if (i > 0 && t < kH) {
            const float* vr = s_v + t * kC;
            float acc = 0.0f;
            #pragma unroll
            for (int c = 0; c < kC; c++) acc += vr[c] * s_dx[c];
            s_y[t] += 0.5f * (s_e[t] + acc);
        }
        __syncthreads();

        if (i < kT - 1) {
            // ===== phase A: dx_{i+1}, prefetch x_{i+2} =====
            if (t < kC) {
                float xi = x_next;
                s_dx[t] = xi - x_reg;
                x_reg = xi;
                if (i + 2 < kT)
                    x_next = (t == 0) ? ts[i + 2] : ysb[(size_t)(i + 2) * kD + (t - 1)];
            }
            __syncthreads();
            // ===== phase B: e = v . dx ; yhat update ; next inp =====
            if (t < kH) {
                const float* vr = s_v + t * kC;
                float e = 0.0f;
                #pragma unroll
                for (int c = 0; c < kC; c++) e += vr[c] * s_dx[c];
                s_e[t] = e;
                float yh = 2.0f * s_y[t] - s_yhat[t] + e;
                s_yhat[t] = yh;
                s_inp[1 + t] = yh;
            }
            if (t == 0) s_inp[0] = x_reg;   // = ts[i+1]
            __syncthreads();
        }
    }

    // ---------------- readout ----------------
    __syncthreads();
    if (t == 0) {
        float acc = rb[0];
        #pragma unroll
        for (int h = 0; h < kH; h++) acc += s_y[h] * rW[h];
        out[b] = acc;
    }
}

extern "C" void kernel_launch(void* const* d_in, const int* in_sizes, int n_in,
                              void* d_out, int out_size, void* d_ws, size_t ws_size,
                              hipStream_t stream)
{
    const float* ts  = (const float*)d_in[0];
    const float* ys  = (const float*)d_in[1];
    const float* iW0 = (const float*)d_in[2];
    const float* ib0 = (const float*)d_in[3];
    const float* iW1 = (const float*)d_in[4];
    const float* ib1 = (const float*)d_in[5];
    const float* iW2 = (const float*)d_in[6];
    const float* ib2 = (const float*)d_in[7];
    const float* vW0 = (const float*)d_in[8];
    const float* vb0 = (const float*)d_in[9];
    const float* vW1 = (const float*)d_in[10];
    const float* vb1 = (const float*)d_in[11];
    const float* vW2 = (const float*)d_in[12];
    const float* vb2 = (const float*)d_in[13];
    const float* rW  = (const float*)d_in[14];
    const float* rb  = (const float*)d_in[15];
    float* out = (float*)d_out;

    hipLaunchKernelGGL(cde_kernel, dim3(kB), dim3(BLOCK), 0, stream,
                       ts, ys, iW0, ib0, iW1, ib1, iW2, ib2,
                       vW0, vb0, vW1, vb1, vW2, vb2, rW, rb, out);
}

// Round 4
// 6449.524 us; speedup vs baseline: 8.4291x; 4.6282x over previous
//
#include <hip/hip_runtime.h>
#include <math.h>

constexpr int kB  = 128;
constexpr int kT  = 1024;
constexpr int kD  = 32;
constexpr int kH  = 64;
constexpr int kW  = 128;
constexpr int kC  = kD + 1;    // 33
constexpr int kO  = kH * kC;   // 2112
constexpr int kIN = kH + 1;    // 65
constexpr int BLOCK = 1024;    // 16 waves

// ---- int16 workspace layout (u32 units) ----
// W2: transposed tiles: uint4 index (R*16+q)*64 + r ; R=row>>6, r=row&63, q=0..15
constexpr int WS_W2  = 0;            // 135168 u32 (2112 rows * 64 words)
constexpr int WS_W1  = 135168;       // 8192 u32  (128 rows * 64 words, row-major)
constexpr int WS_W0  = 143360;       // 4224 u32  (128 rows * 33 words, 65 cols + pad)
constexpr int WS_SC2 = 147584;       // 2112 f32 row scales
constexpr int WS_SC1 = 149696;       // 128
constexpr int WS_SC0 = 149824;       // 128
constexpr int WS_TOT = 149952;       // u32 -> 599,808 bytes

__device__ __forceinline__ float fast_sigmoid(float x) { return 1.0f / (1.0f + __expf(-x)); }
__device__ __forceinline__ float lipswish_f(float x)   { return 0.909f * x * fast_sigmoid(x); }
__device__ __forceinline__ float fast_tanh(float x) {
    float ax = fabsf(x);
    float e  = __expf(2.0f * ax);
    float r  = 1.0f - 2.0f / (e + 1.0f);
    return copysignf(r, x);
}
__device__ __forceinline__ float dot4(float4 a, float4 b) {
    return a.x * b.x + a.y * b.y + a.z * b.z + a.w * b.w;
}
// acc += dot(int16 pair in u, z0, z1)
__device__ __forceinline__ float fma2i(unsigned u, float z0, float z1, float acc) {
    int lo = (int)(short)(u & 0xffffu);
    int hi = ((int)u) >> 16;
    acc += (float)lo * z0 + (float)hi * z1;
    return acc;
}
__device__ __forceinline__ float fma8i(uint4 u, float4 zl, float4 zh, float acc) {
    acc = fma2i(u.x, zl.x, zl.y, acc);
    acc = fma2i(u.y, zl.z, zl.w, acc);
    acc = fma2i(u.z, zh.x, zh.y, acc);
    acc = fma2i(u.w, zh.z, zh.w, acc);
    return acc;
}
__device__ __forceinline__ int q15(float w, float inv) {
    float q = rintf(w * inv);
    q = fmaxf(-32767.0f, fminf(32767.0f, q));
    return (int)q;
}
__device__ __forceinline__ unsigned pack16(int a, int b) {
    return ((unsigned)a & 0xffffu) | ((unsigned)b << 16);
}

// one wave (64 threads) per row; rows: [0,2112) W2, [2112,2240) W1, [2240,2368) W0
__global__ __launch_bounds__(64)
void prep_kernel(const float* __restrict__ vW0, const float* __restrict__ vW1,
                 const float* __restrict__ vW2, unsigned* __restrict__ ws)
{
    const int row  = blockIdx.x;
    const int lane = threadIdx.x;
    float* scf = (float*)ws;

    if (row < kO) {                                   // vW2 row, 128 cols
        const float* src = vW2 + (size_t)row * kW;
        float m = fmaxf(fabsf(src[lane]), fabsf(src[lane + 64]));
        #pragma unroll
        for (int s = 1; s < 64; s <<= 1) m = fmaxf(m, __shfl_xor(m, s));
        float inv = (m > 0.0f) ? 32767.0f / m : 0.0f;
        if (lane == 0) scf[WS_SC2 + row] = (m > 0.0f) ? m / 32767.0f : 0.0f;
        // lane writes word w = lane : cols 2w, 2w+1 -> transposed tile index
        int w = lane;
        unsigned pk = pack16(q15(src[2 * w], inv), q15(src[2 * w + 1], inv));
        int R = row >> 6, r = row & 63, q = w >> 2, e = w & 3;
        ws[WS_W2 + (((R * 16 + q) * 64 + r) << 2) + e] = pk;
    } else if (row < kO + kW) {                       // vW1 row, 128 cols
        int r = row - kO;
        const float* src = vW1 + (size_t)r * kW;
        float m = fmaxf(fabsf(src[lane]), fabsf(src[lane + 64]));
        #pragma unroll
        for (int s = 1; s < 64; s <<= 1) m = fmaxf(m, __shfl_xor(m, s));
        float inv = (m > 0.0f) ? 32767.0f / m : 0.0f;
        if (lane == 0) scf[WS_SC1 + r] = (m > 0.0f) ? m / 32767.0f : 0.0f;
        int w = lane;
        ws[WS_W1 + r * 64 + w] = pack16(q15(src[2 * w], inv), q15(src[2 * w + 1], inv));
    } else {                                          // vW0 row, 65 cols
        int r = row - kO - kW;
        const float* src = vW0 + (size_t)r * kIN;
        float m = fabsf(src[lane]);
        if (lane == 0) m = fmaxf(m, fabsf(src[64]));
        #pragma unroll
        for (int s = 1; s < 64; s <<= 1) m = fmaxf(m, __shfl_xor(m, s));
        float inv = (m > 0.0f) ? 32767.0f / m : 0.0f;
        if (lane == 0) scf[WS_SC0 + r] = (m > 0.0f) ? m / 32767.0f : 0.0f;
        if (lane < 33) {
            int c0 = 2 * lane, c1 = 2 * lane + 1;
            int qa = q15(src[c0], inv);
            int qb = (c1 < kIN) ? q15(src[c1], inv) : 0;
            ws[WS_W0 + r * 33 + lane] = pack16(qa, qb);
        }
    }
}

template <int QI>
__global__ __launch_bounds__(BLOCK)
void cde_kernel(
    const float* __restrict__ ts,  const float* __restrict__ ys,
    const float* __restrict__ iW0, const float* __restrict__ ib0,
    const float* __restrict__ iW1, const float* __restrict__ ib1,
    const float* __restrict__ iW2, const float* __restrict__ ib2,
    const float* __restrict__ vW0, const float* __restrict__ vb0,
    const float* __restrict__ vW1, const float* __restrict__ vb1,
    const float* __restrict__ vW2, const float* __restrict__ vb2,
    const float* __restrict__ rW,  const float* __restrict__ rb,
    const unsigned* __restrict__ wsb,
    float* __restrict__ out)
{
    const int b  = blockIdx.x;
    const int t  = threadIdx.x;
    const int r8 = t >> 3;     // 0..127
    const int g  = t & 7;      // 0..7
    const int wv = t >> 6;     // wave 0..15
    const int ln = t & 63;     // lane

    __shared__ __align__(16) float s_v[kO];
    __shared__ __align__(16) float s_z1[kW], s_z2[kW];
    __shared__ __align__(16) float s_inp[kIN + 1];   // [65] = 0 pad
    __shared__ float s_y[kH], s_yhat[kH], s_e[kH];
    __shared__ float s_dx[kC];

    const float*    ysb   = ys + (size_t)b * kT * kD;
    const uint4*    wsW2q = (const uint4*)(wsb + WS_W2);
    const unsigned* wsW1  = wsb + WS_W1;
    const unsigned* wsW0  = wsb + WS_W0;
    const float*    scf   = (const float*)wsb;

    const float bA  = vb2[t];
    const float bB  = vb2[t + 1024];
    const float bTl = (t < 512) ? vb2[2048 + r8] : 0.0f;
    const float b0r = vb0[r8];
    const float b1r = vb1[r8];
    const float sA  = QI ? scf[WS_SC2 + t] : 0.0f;
    const float sB  = QI ? scf[WS_SC2 + t + 1024] : 0.0f;
    const float sTl = (QI && t < 512) ? scf[WS_SC2 + 2048 + r8] : 0.0f;
    const float s0r = QI ? scf[WS_SC0 + r8] : 0.0f;
    const float s1r = QI ? scf[WS_SC1 + r8] : 0.0f;

    // ---- x0 + prefetch x1
    float x_reg = 0.0f, x_next = 0.0f;
    if (t < kC) {
        x_reg  = (t == 0) ? ts[0] : ysb[t - 1];
        x_next = (t == 0) ? ts[1] : ysb[kD + (t - 1)];
        s_dx[t] = x_reg;                    // temp staging for initial MLP
    }
    if (t == 0) s_inp[kIN] = 0.0f;          // pad
    __syncthreads();

    // ---- initial MLP (one-time, fp32)
    if (t < kW) {
        const float* wrow = iW0 + t * kC;
        float acc = ib0[t];
        #pragma unroll
        for (int c = 0; c < kC; c++) acc += wrow[c] * s_dx[c];
        s_z1[t] = fmaxf(acc, 0.0f);
    }
    __syncthreads();
    if (t < kW) {
        const float4* wr = (const float4*)(iW1 + t * kW);
        const float4* z4 = (const float4*)s_z1;
        float acc = ib1[t];
        #pragma unroll 8
        for (int q = 0; q < kW / 4; q++) acc += dot4(wr[q], z4[q]);
        s_z2[t] = fmaxf(acc, 0.0f);
    }
    __syncthreads();
    if (t < kH) {
        const float4* wr = (const float4*)(iW2 + t * kW);
        const float4* z4 = (const float4*)s_z2;
        float acc = ib2[t];
        #pragma unroll 8
        for (int q = 0; q < kW / 4; q++) acc += dot4(wr[q], z4[q]);
        s_y[t] = acc; s_yhat[t] = acc;
        s_inp[1 + t] = acc;
    }
    if (t == 0) s_inp[0] = x_reg;           // ts[0]
    __syncthreads();

    // ---- main scan
    for (int i = 0; i < kT; i++) {
        // ===== layer 1: 65->128, split-k-8, row r8 =====
        {
            float acc = 0.0f;
            if (QI) {
                const unsigned* rowp = wsW0 + r8 * 33;
                #pragma unroll
                for (int m = 0; m < 5; m++) {
                    int p = g + 8 * m;
                    if (p < 33) acc = fma2i(rowp[p], s_inp[2 * p], s_inp[2 * p + 1], acc);
                }
            } else {
                const float* rowp = vW0 + r8 * kIN;
                #pragma unroll
                for (int m = 0; m < 5; m++) {
                    int p = g + 8 * m;
                    if (p < 33) {
                        float w0 = rowp[2 * p];
                        float w1 = (2 * p + 1 < kIN) ? rowp[2 * p + 1] : 0.0f;
                        acc += w0 * s_inp[2 * p] + w1 * s_inp[2 * p + 1];
                    }
                }
            }
            acc += __shfl_xor(acc, 1);
            acc += __shfl_xor(acc, 2);
            acc += __shfl_xor(acc, 4);
            if (g == 0) s_z1[r8] = lipswish_f(b0r + (QI ? s0r * acc : acc));
        }
        __syncthreads();
        // ===== layer 2: 128->128, split-k-8, row r8 =====
        {
            float acc = 0.0f;
            #pragma unroll
            for (int m = 0; m < 2; m++) {
                int ch = g + 8 * m;                 // chunk of 8 cols
                int c0 = 8 * ch;
                const float4* z4 = (const float4*)(s_z1 + c0);
                float4 za = z4[0], zb = z4[1];
                if (QI) {
                    uint4 u = *(const uint4*)(wsW1 + r8 * 64 + 4 * ch);
                    acc = fma8i(u, za, zb, acc);
                } else {
                    const float* wr = vW1 + r8 * kW + c0;
                    acc += dot4(*(const float4*)wr, za) + dot4(*(const float4*)(wr + 4), zb);
                }
            }
            acc += __shfl_xor(acc, 1);
            acc += __shfl_xor(acc, 2);
            acc += __shfl_xor(acc, 4);
            if (g == 0) s_z2[r8] = lipswish_f(b1r + (QI ? s1r * acc : acc));
        }
        __syncthreads();
        // ===== layer 3 main: rows t (group wv) and t+1024 (group wv+16) =====
        {
            float acc0 = 0.0f, acc1 = 0.0f;
            if (QI) {
                const uint4* pA = wsW2q + (size_t)(wv * 16) * 64 + ln;
                const uint4* pB = wsW2q + (size_t)((wv + 16) * 16) * 64 + ln;
                #pragma unroll 2
                for (int m = 0; m < 8; m++) {
                    const float4* z4 = (const float4*)(s_z2 + 16 * m);
                    float4 z0 = z4[0], z1 = z4[1], z2 = z4[2], z3 = z4[3];
                    uint4 a0 = pA[(2 * m) * 64],     a1 = pA[(2 * m + 1) * 64];
                    uint4 c0 = pB[(2 * m) * 64],     c1 = pB[(2 * m + 1) * 64];
                    acc0 = fma8i(a0, z0, z1, acc0);
                    acc0 = fma8i(a1, z2, z3, acc0);
                    acc1 = fma8i(c0, z0, z1, acc1);
                    acc1 = fma8i(c1, z2, z3, acc1);
                }
                s_v[t]        = fast_tanh(bA + sA * acc0);
                s_v[t + 1024] = fast_tanh(bB + sB * acc1);
            } else {
                #pragma unroll 2
                for (int m = 0; m < 8; m++) {
                    const float4* z4 = (const float4*)(s_z2 + 16 * m);
                    float4 z0 = z4[0], z1 = z4[1], z2 = z4[2], z3 = z4[3];
                    const float4* rA = (const float4*)(vW2 + (size_t)t * kW + 16 * m);
                    const float4* rB = (const float4*)(vW2 + (size_t)(t + 1024) * kW + 16 * m);
                    acc0 += dot4(rA[0], z0) + dot4(rA[1], z1) + dot4(rA[2], z2) + dot4(rA[3], z3);
                    acc1 += dot4(rB[0], z0) + dot4(rB[1], z1) + dot4(rB[2], z2) + dot4(rB[3], z3);
                }
                s_v[t]        = fast_tanh(bA + acc0);
                s_v[t + 1024] = fast_tanh(bB + acc1);
            }
        }
        // ===== layer 3 tail: rows 2048..2111 (group 32), split-k-8 =====
        if (t < 512) {
            int c0 = 16 * g;
            const float4* z4 = (const float4*)(s_z2 + c0);
            float4 z0 = z4[0], z1 = z4[1], z2 = z4[2], z3 = z4[3];
            float acc = 0.0f;
            if (QI) {
                uint4 u0 = wsW2q[(size_t)(32 * 16 + 2 * g) * 64 + r8];
                uint4 u1 = wsW2q[(size_t)(32 * 16 + 2 * g + 1) * 64 + r8];
                acc = fma8i(u0, z0, z1, acc);
                acc = fma8i(u1, z2, z3, acc);
            } else {
                const float4* wr = (const float4*)(vW2 + (size_t)(2048 + r8) * kW + c0);
                acc += dot4(wr[0], z0) + dot4(wr[1], z1) + dot4(wr[2], z2) + dot4(wr[3], z3);
            }
            acc += __shfl_xor(acc, 1);
            acc += __shfl_xor(acc, 2);
            acc += __shfl_xor(acc, 4);
            if (g == 0) s_v[2048 + r8] = fast_tanh(bTl + (QI ? sTl * acc : acc));
        }
        __syncthreads();

        // ===== y update (uses dx_i, e_i from previous phase B) =====
        if (i > 0 && t < kH) {
            const float* vr = s_v + t * kC;
            float acc = 0.0f;
            #pragma unroll
            for (int c = 0; c < kC; c++) acc += vr[c] * s_dx[c];
            s_y[t] += 0.5f * (s_e[t] + acc);
        }
        __syncthreads();

        if (i < kT - 1) {
            // phase A: dx_{i+1}, prefetch x_{i+2}
            if (t < kC) {
                float xi = x_next;
                s_dx[t] = xi - x_reg;
                x_reg = xi;
                if (i + 2 < kT)
                    x_next = (t == 0) ? ts[i + 2] : ysb[(size_t)(i + 2) * kD + (t - 1)];
            }
            __syncthreads();
            // phase B: e = v.dx ; yhat update ; next vf input
            if (t < kH) {
                const float* vr = s_v + t * kC;
                float e = 0.0f;
                #pragma unroll
                for (int c = 0; c < kC; c++) e += vr[c] * s_dx[c];
                s_e[t] = e;
                float yh = 2.0f * s_y[t] - s_yhat[t] + e;
                s_yhat[t] = yh;
                s_inp[1 + t] = yh;
            }
            if (t == 0) s_inp[0] = x_reg;   // = ts[i+1]
            __syncthreads();
        }
    }

    // ---- readout
    __syncthreads();
    if (t == 0) {
        float acc = rb[0];
        #pragma unroll
        for (int h = 0; h < kH; h++) acc += s_y[h] * rW[h];
        out[b] = acc;
    }
}

extern "C" void kernel_launch(void* const* d_in, const int* in_sizes, int n_in,
                              void* d_out, int out_size, void* d_ws, size_t ws_size,
                              hipStream_t stream)
{
    const float* ts  = (const float*)d_in[0];
    const float* ys  = (const float*)d_in[1];
    const float* iW0 = (const float*)d_in[2];
    const float* ib0 = (const float*)d_in[3];
    const float* iW1 = (const float*)d_in[4];
    const float* ib1 = (const float*)d_in[5];
    const float* iW2 = (const float*)d_in[6];
    const float* ib2 = (const float*)d_in[7];
    const float* vW0 = (const float*)d_in[8];
    const float* vb0 = (const float*)d_in[9];
    const float* vW1 = (const float*)d_in[10];
    const float* vb1 = (const float*)d_in[11];
    const float* vW2 = (const float*)d_in[12];
    const float* vb2 = (const float*)d_in[13];
    const float* rW  = (const float*)d_in[14];
    const float* rb  = (const float*)d_in[15];
    float* out = (float*)d_out;
    unsigned* ws = (unsigned*)d_ws;

    if (ws_size >= (size_t)WS_TOT * 4) {
        hipLaunchKernelGGL(prep_kernel, dim3(kO + kW + kW), dim3(64), 0, stream,
                           vW0, vW1, vW2, ws);
        hipLaunchKernelGGL((cde_kernel<1>), dim3(kB), dim3(BLOCK), 0, stream,
                           ts, ys, iW0, ib0, iW1, ib1, iW2, ib2,
                           vW0, vb0, vW1, vb1, vW2, vb2, rW, rb, ws, out);
    } else {
        hipLaunchKernelGGL((cde_kernel<0>), dim3(kB), dim3(BLOCK), 0, stream,
                           ts, ys, iW0, ib0, iW1, ib1, iW2, ib2,
                           vW0, vb0, vW1, vb1, vW2, vb2, rW, rb, ws, out);
    }
}